// Round 6
// baseline (767.294 us; speedup 1.0000x reference)
//
#include <hip/hip_runtime.h>
#include <hip/hip_bf16.h>

#define N_TOK 8192
#define DM 1024
#define KD 64
#define ODIM 1024
#define LOG2E 1.4426950408889634f

typedef unsigned short ushort_t;
typedef __attribute__((ext_vector_type(8))) short short8;
typedef __attribute__((ext_vector_type(4))) float f32x4;

#define MFMA16(a, b, c) __builtin_amdgcn_mfma_f32_16x16x32_bf16((a), (b), (c), 0, 0, 0)

__device__ __forceinline__ float ex2(float x) {
#if __has_builtin(__builtin_amdgcn_exp2f)
    return __builtin_amdgcn_exp2f(x);
#else
    return exp2f(x);
#endif
}
// RNE float->bf16 (finite inputs)
__device__ __forceinline__ ushort_t rne(float x) {
    unsigned u = __float_as_uint(x);
    u += 0x7fffu + ((u >> 16) & 1u);
    return (ushort_t)(u >> 16);
}
__device__ __forceinline__ float ubf(ushort_t h) {
    return __uint_as_float(((unsigned)h) << 16);
}
__device__ __forceinline__ void split2(float x, ushort_t& hi, ushort_t& lo) {
    hi = rne(x);
    lo = rne(x - ubf(hi));
}
__device__ __forceinline__ unsigned bfpack(float a, float b) {
    unsigned ua = __float_as_uint(a); ua += 0x7fffu + ((ua >> 16) & 1u);
    unsigned ub = __float_as_uint(b); ub += 0x7fffu + ((ub >> 16) & 1u);
    return (ua >> 16) | (ub & 0xffff0000u);
}

// device-scope grid barrier (1024 blocks co-resident by __launch_bounds__ arithmetic)
__device__ __forceinline__ void gbar(unsigned* ctr, unsigned target) {
    __syncthreads();
    if (threadIdx.x == 0) {
        __hip_atomic_fetch_add(ctr, 1u, __ATOMIC_ACQ_REL, __HIP_MEMORY_SCOPE_AGENT);
        while (__hip_atomic_load(ctr, __ATOMIC_ACQUIRE, __HIP_MEMORY_SCOPE_AGENT) < target) {
            __builtin_amdgcn_s_sleep(8);
        }
    }
    __syncthreads();
}

// ws offsets (bytes)
#define OFF_WT_HI   0u
#define OFF_WT_LO   393216u
#define OFF_WOT_HI  786432u
#define OFF_WOT_LO  917504u
#define OFF_QHI     1048576u
#define OFF_QLO     2097152u
#define OFF_KHI     3145728u
#define OFF_KLO     4194304u
#define OFF_VT      5242880u
#define OFF_OPART   6291456u
#define OFF_MLPART  14680064u
#define OFF_BAR     14942208u

// One persistent kernel: prep -> qkv -> attention(split-K) -> merge+proj,
// separated by manual grid barriers. 1024 blocks x 256 thr, 4 blocks/CU.
__global__ __launch_bounds__(256, 4) void mega_kernel(
    const float* __restrict__ x, const float* __restrict__ wq,
    const float* __restrict__ bq, const float* __restrict__ wo,
    const float* __restrict__ bo, const int* __restrict__ causal_p,
    float* __restrict__ out, char* __restrict__ ws)
{
    ushort_t* wT_hi  = (ushort_t*)(ws + OFF_WT_HI);
    ushort_t* wT_lo  = (ushort_t*)(ws + OFF_WT_LO);
    ushort_t* woT_hi = (ushort_t*)(ws + OFF_WOT_HI);
    ushort_t* woT_lo = (ushort_t*)(ws + OFF_WOT_LO);
    ushort_t* q_hi   = (ushort_t*)(ws + OFF_QHI);
    ushort_t* q_lo   = (ushort_t*)(ws + OFF_QLO);
    ushort_t* k_hi   = (ushort_t*)(ws + OFF_KHI);
    ushort_t* k_lo   = (ushort_t*)(ws + OFF_KLO);
    ushort_t* vT     = (ushort_t*)(ws + OFF_VT);
    float*    Opart  = (float*)(ws + OFF_OPART);
    float*    MLpart = (float*)(ws + OFF_MLPART);
    unsigned* bar    = (unsigned*)(ws + OFF_BAR);

    __shared__ union {
        struct { float Om[4 * 1088]; float ml[128]; } p2;   // Om[wv][d:64][qrow:16 pad17]
        struct { ushort_t aoh[16 * 72]; ushort_t aol[16 * 72]; } p3;
    } sm;

    const int tid = threadIdx.x;
    const int wv = tid >> 6, lane = tid & 63, g = lane >> 4, i = lane & 15;
    const int causal = *causal_p;
    const f32x4 zero4 = {0.f, 0.f, 0.f, 0.f};

    // ---------- Phase 0: weight transpose + hi/lo split ----------
    {
        const int gtid = (int)blockIdx.x * 256 + tid;  // exactly 262144 = 192K + 64K
        if (gtid < 192 * 1024) {
            const int c = gtid >> 10, k = gtid & 1023;
            ushort_t h, l; split2(wq[k * 192 + c], h, l);
            wT_hi[gtid] = h; wT_lo[gtid] = l;
        } else {
            const int j = gtid - 192 * 1024;
            const int c = j >> 6, k = j & 63;
            ushort_t h, l; split2(wo[k * ODIM + c], h, l);
            woT_hi[j] = h; woT_lo[j] = l;
        }
    }
    gbar(bar, 1024u);

    // ---------- Phase 1: QKV projection (MFMA hi/lo) ----------
    // 1536 work-units: rows (wu/3)*16, col-tile ctid=(wu%3)*4+wv
    for (int rep = 0; rep < 2; ++rep) {
        const int wu = (int)blockIdx.x + (rep << 10);
        if (wu < 1536) {
            const int R0 = (wu / 3) * 16;
            const int ctid = (wu % 3) * 4 + wv;
            f32x4 acc = zero4;
            const float* xp = &x[(size_t)(R0 + i) * DM + g * 8];
            const ushort_t* bhp = &wT_hi[(ctid * 16 + i) * DM + g * 8];
            const ushort_t* blp = &wT_lo[(ctid * 16 + i) * DM + g * 8];
            for (int kc = 0; kc < 32; ++kc) {
                const float4 xa = *(const float4*)(xp + kc * 32);
                const float4 xb = *(const float4*)(xp + kc * 32 + 4);
                const float xe[8] = {xa.x, xa.y, xa.z, xa.w, xb.x, xb.y, xb.z, xb.w};
                union { short8 v; ushort_t u[8]; } ah, al;
#pragma unroll
                for (int j = 0; j < 8; ++j) { split2(xe[j], ah.u[j], al.u[j]); }
                const short8 bh = *(const short8*)(bhp + kc * 32);
                const short8 bl = *(const short8*)(blp + kc * 32);
                acc = MFMA16(ah.v, bh, acc);
                acc = MFMA16(ah.v, bl, acc);
                acc = MFMA16(al.v, bh, acc);
            }
            const int c = ctid * 16 + i;
            const float bias = bq[c];
            if (ctid < 4) {          // q: pre-scale by log2e (softmax in exp2 domain)
#pragma unroll
                for (int reg = 0; reg < 4; ++reg) {
                    ushort_t h, l; split2((acc[reg] + bias) * LOG2E, h, l);
                    q_hi[(R0 + 4 * g + reg) * KD + c] = h;
                    q_lo[(R0 + 4 * g + reg) * KD + c] = l;
                }
            } else if (ctid < 8) {   // k
                const int c2 = c - 64;
#pragma unroll
                for (int reg = 0; reg < 4; ++reg) {
                    ushort_t h, l; split2(acc[reg] + bias, h, l);
                    k_hi[(R0 + 4 * g + reg) * KD + c2] = h;
                    k_lo[(R0 + 4 * g + reg) * KD + c2] = l;
                }
            } else {                 // v -> transposed bf16
                union { ushort_t u[4]; uint2 v; } pk;
#pragma unroll
                for (int reg = 0; reg < 4; ++reg) pk.u[reg] = rne(acc[reg] + bias);
                *(uint2*)&vT[(size_t)(c - 128) * N_TOK + R0 + 4 * g] = pk.v;
            }
        }
    }
    gbar(bar, 2048u);

    // ---------- Phase 2: split-K causal flash attention (S^T form) ----------
    // 2048 wu; block pairs (b, 2047-b) for balance. wu -> qt=511-(wu>>2), s=wu&3.
    // Permuted key->tile map: tile ct holds keys 32(ct>>1)+4(ct&1)+8g+reg, so the
    // P^T B-fragment for O^T = V^T P^T is the lane's own registers repacked.
    {
        const int koff[4] = {0, 4, 32, 36};
        const int ibase = ((i >> 2) << 3) + (i & 3);
        for (int rep = 0; rep < 2; ++rep) {
            const int wu = (rep == 0) ? (int)blockIdx.x : 2047 - (int)blockIdx.x;
            const int qt = 511 - (wu >> 2);
            const int s = wu & 3;
            const int R0 = qt << 4;
            const int nkt = causal ? (R0 >> 6) + 1 : (N_TOK / 64);
            const int c0 = (s * nkt) >> 2, c1 = ((s + 1) * nkt) >> 2;

            const short8 qh0 = *(const short8*)&q_hi[(R0 + i) * KD + g * 8];
            const short8 qh1 = *(const short8*)&q_hi[(R0 + i) * KD + 32 + g * 8];
            const short8 ql0 = *(const short8*)&q_lo[(R0 + i) * KD + g * 8];
            const short8 ql1 = *(const short8*)&q_lo[(R0 + i) * KD + 32 + g * 8];

            f32x4 o4[4] = {zero4, zero4, zero4, zero4};
            float runm = -1e30f, runl = 0.f;

            for (int t = c0 + wv; t < c1; t += 4) {
                const int kb = t << 6;
                f32x4 s4[4];
#pragma unroll
                for (int ct = 0; ct < 4; ++ct) {
                    const int row = (kb + koff[ct] + ibase) * KD;
                    const short8 kh0 = *(const short8*)&k_hi[row + g * 8];
                    const short8 kh1 = *(const short8*)&k_hi[row + 32 + g * 8];
                    const short8 kl0 = *(const short8*)&k_lo[row + g * 8];
                    const short8 kl1 = *(const short8*)&k_lo[row + 32 + g * 8];
                    f32x4 a = MFMA16(kh0, qh0, zero4);
                    a = MFMA16(kh1, qh1, a);
                    a = MFMA16(kh0, ql0, a);
                    a = MFMA16(kh1, ql1, a);
                    a = MFMA16(kl0, qh0, a);
                    a = MFMA16(kl1, qh1, a);
                    s4[ct] = a;
                }
                if (causal && (kb + 64 > R0)) {  // diagonal tile only
#pragma unroll
                    for (int ct = 0; ct < 4; ++ct)
#pragma unroll
                        for (int reg = 0; reg < 4; ++reg) {
                            const int key = kb + koff[ct] + (g << 3) + reg;
                            s4[ct][reg] = (key <= R0 + i) ? s4[ct][reg] : -1e30f;
                        }
                }
                // online softmax: lane owns qrow i; scalar state
                float mx = -1e30f;
#pragma unroll
                for (int ct = 0; ct < 4; ++ct)
#pragma unroll
                    for (int reg = 0; reg < 4; ++reg) mx = fmaxf(mx, s4[ct][reg]);
                mx = fmaxf(mx, __shfl_xor(mx, 16));
                mx = fmaxf(mx, __shfl_xor(mx, 32));
                const float nm = fmaxf(runm, mx);
                const float al = ex2(runm - nm);
                runm = nm;
                float rs = 0.f;
#pragma unroll
                for (int ct = 0; ct < 4; ++ct)
#pragma unroll
                    for (int reg = 0; reg < 4; ++reg) {
                        const float p = ex2(s4[ct][reg] - nm);
                        s4[ct][reg] = p;
                        rs += p;
                    }
                rs += __shfl_xor(rs, 16);
                rs += __shfl_xor(rs, 32);
                runl = runl * al + rs;
#pragma unroll
                for (int ct2 = 0; ct2 < 4; ++ct2)
#pragma unroll
                    for (int reg = 0; reg < 4; ++reg) o4[ct2][reg] *= al;
                // P^T B-frags: pure register repack
                unsigned pk0[2], pk1[2], pk2[2], pk3[2];
                pk0[0] = bfpack(s4[0][0], s4[0][1]); pk0[1] = bfpack(s4[0][2], s4[0][3]);
                pk1[0] = bfpack(s4[1][0], s4[1][1]); pk1[1] = bfpack(s4[1][2], s4[1][3]);
                pk2[0] = bfpack(s4[2][0], s4[2][1]); pk2[1] = bfpack(s4[2][2], s4[2][3]);
                pk3[0] = bfpack(s4[3][0], s4[3][1]); pk3[1] = bfpack(s4[3][2], s4[3][3]);
                short8 pb0, pb1;
                {
                    union { unsigned w[4]; short8 v; } u;
                    u.w[0] = pk0[0]; u.w[1] = pk0[1]; u.w[2] = pk1[0]; u.w[3] = pk1[1];
                    pb0 = u.v;
                    u.w[0] = pk2[0]; u.w[1] = pk2[1]; u.w[2] = pk3[0]; u.w[3] = pk3[1];
                    pb1 = u.v;
                }
#pragma unroll
                for (int ct2 = 0; ct2 < 4; ++ct2) {
                    const int vrow = (ct2 * 16 + i) * N_TOK + kb;
                    const short8 va0 = *(const short8*)&vT[vrow + g * 8];
                    const short8 va1 = *(const short8*)&vT[vrow + 32 + g * 8];
                    o4[ct2] = MFMA16(va0, pb0, o4[ct2]);
                    o4[ct2] = MFMA16(va1, pb1, o4[ct2]);
                }
            }

            // 4-wave combine -> unnormalized partial (qt, s)
#pragma unroll
            for (int ct2 = 0; ct2 < 4; ++ct2)
#pragma unroll
                for (int reg = 0; reg < 4; ++reg)
                    sm.p2.Om[wv * 1088 + (ct2 * 16 + 4 * g + reg) * 17 + i] = o4[ct2][reg];
            if (lane < 16) {
                sm.p2.ml[wv * 32 + lane] = runm;
                sm.p2.ml[wv * 32 + 16 + lane] = runl;
            }
            __syncthreads();
            {
                const int d = tid & 63, rb2 = (tid >> 6) << 2;
                const int pidx = (qt << 2) + s;
#pragma unroll
                for (int rr = 0; rr < 4; ++rr) {
                    const int r = rb2 + rr;
                    const float m0 = sm.p2.ml[r],      m1 = sm.p2.ml[32 + r];
                    const float m2 = sm.p2.ml[64 + r], m3 = sm.p2.ml[96 + r];
                    const float M = fmaxf(fmaxf(m0, m1), fmaxf(m2, m3));
                    const float e0 = ex2(m0 - M), e1 = ex2(m1 - M);
                    const float e2 = ex2(m2 - M), e3 = ex2(m3 - M);
                    const float L = sm.p2.ml[16 + r] * e0 + sm.p2.ml[48 + r] * e1 +
                                    sm.p2.ml[80 + r] * e2 + sm.p2.ml[112 + r] * e3;
                    const float O = sm.p2.Om[d * 17 + r] * e0 +
                                    sm.p2.Om[1088 + d * 17 + r] * e1 +
                                    sm.p2.Om[2176 + d * 17 + r] * e2 +
                                    sm.p2.Om[3264 + d * 17 + r] * e3;
                    Opart[((size_t)pidx * 16 + r) * 64 + d] = O;
                    if (d == 0) {
                        MLpart[pidx * 32 + r] = M;
                        MLpart[pidx * 32 + 16 + r] = L;
                    }
                }
            }
            __syncthreads();
        }
    }
    gbar(bar, 3072u);

    // ---------- Phase 3: split-K merge + output projection ----------
    // 2048 wu: R0=(wu>>2)*16, col-quarter qa=wu&3; wave: 4 col-tiles
    for (int rep = 0; rep < 2; ++rep) {
        const int wu = (int)blockIdx.x + (rep << 10);
        const int qtile = wu >> 2, qa = wu & 3;
        const int R0 = qtile << 4;
        {
            const int d = tid & 63, rb2 = (tid >> 6) << 2;
#pragma unroll
            for (int rr = 0; rr < 4; ++rr) {
                const int r = rb2 + rr;
                float m[4], l[4];
#pragma unroll
                for (int s2 = 0; s2 < 4; ++s2) {
                    m[s2] = MLpart[((qtile << 2) + s2) * 32 + r];
                    l[s2] = MLpart[((qtile << 2) + s2) * 32 + 16 + r];
                }
                const float M = fmaxf(fmaxf(m[0], m[1]), fmaxf(m[2], m[3]));
                float den = 0.f, O = 0.f;
#pragma unroll
                for (int s2 = 0; s2 < 4; ++s2) {
                    const float e = ex2(m[s2] - M);
                    den += l[s2] * e;
                    O += Opart[((size_t)((qtile << 2) + s2) * 16 + r) * 64 + d] * e;
                }
                ushort_t h, lo2; split2(O / den, h, lo2);
                sm.p3.aoh[r * 72 + d] = h;
                sm.p3.aol[r * 72 + d] = lo2;
            }
        }
        __syncthreads();
        {
            const short8 ah0 = *(const short8*)&sm.p3.aoh[i * 72 + g * 8];
            const short8 ah1 = *(const short8*)&sm.p3.aoh[i * 72 + 32 + g * 8];
            const short8 al0 = *(const short8*)&sm.p3.aol[i * 72 + g * 8];
            const short8 al1 = *(const short8*)&sm.p3.aol[i * 72 + 32 + g * 8];
#pragma unroll
            for (int cc = 0; cc < 4; ++cc) {
                const int col = (qa << 8) + ((wv << 2) + cc) * 16 + i;
                const short8 bh0 = *(const short8*)&woT_hi[col * KD + g * 8];
                const short8 bh1 = *(const short8*)&woT_hi[col * KD + 32 + g * 8];
                const short8 bl0 = *(const short8*)&woT_lo[col * KD + g * 8];
                const short8 bl1 = *(const short8*)&woT_lo[col * KD + 32 + g * 8];
                f32x4 acc = MFMA16(ah0, bh0, zero4);
                acc = MFMA16(ah1, bh1, acc);
                acc = MFMA16(ah0, bl0, acc);
                acc = MFMA16(ah1, bl1, acc);
                acc = MFMA16(al0, bh0, acc);
                acc = MFMA16(al1, bh1, acc);
                const float bias = bo[col];
#pragma unroll
                for (int reg = 0; reg < 4; ++reg)
                    out[(size_t)(R0 + 4 * g + reg) * ODIM + col] = acc[reg] + bias;
            }
        }
        __syncthreads();
    }
}

extern "C" void kernel_launch(void* const* d_in, const int* in_sizes, int n_in,
                              void* d_out, int out_size, void* d_ws, size_t ws_size,
                              hipStream_t stream) {
    const float* x     = (const float*)d_in[0];
    const float* w_qkv = (const float*)d_in[1];
    const float* b_qkv = (const float*)d_in[2];
    const float* w_out = (const float*)d_in[3];
    const float* b_out = (const float*)d_in[4];
    const int* causal  = (const int*)d_in[5];
    float* out         = (float*)d_out;
    char* ws           = (char*)d_ws;

    // zero the grid-barrier counter (ws is poisoned 0xAA before every launch)
    hipMemsetAsync(ws + OFF_BAR, 0, 64, stream);
    mega_kernel<<<1024, 256, 0, stream>>>(x, w_qkv, b_qkv, w_out, b_out, causal, out, ws);
}

// Round 7
// 292.001 us; speedup vs baseline: 2.6277x; 2.6277x over previous
//
#include <hip/hip_runtime.h>
#include <hip/hip_bf16.h>

#define N_TOK 8192
#define DM 1024
#define KD 64
#define ODIM 1024
#define LOG2E 1.4426950408889634f

typedef unsigned short ushort_t;
typedef __attribute__((ext_vector_type(8))) short short8;
typedef __attribute__((ext_vector_type(4))) float f32x4;

#define MFMA16(a, b, c) __builtin_amdgcn_mfma_f32_16x16x32_bf16((a), (b), (c), 0, 0, 0)

__device__ __forceinline__ float ex2(float x) {
#if __has_builtin(__builtin_amdgcn_exp2f)
    return __builtin_amdgcn_exp2f(x);
#else
    return exp2f(x);
#endif
}
// RNE float->bf16 (finite inputs)
__device__ __forceinline__ ushort_t rne(float x) {
    unsigned u = __float_as_uint(x);
    u += 0x7fffu + ((u >> 16) & 1u);
    return (ushort_t)(u >> 16);
}
__device__ __forceinline__ float ubf(ushort_t h) {
    return __uint_as_float(((unsigned)h) << 16);
}
__device__ __forceinline__ void split2(float x, ushort_t& hi, ushort_t& lo) {
    hi = rne(x);
    lo = rne(x - ubf(hi));
}
__device__ __forceinline__ unsigned bfpack(float a, float b) {
    unsigned ua = __float_as_uint(a); ua += 0x7fffu + ((ua >> 16) & 1u);
    unsigned ub = __float_as_uint(b); ub += 0x7fffu + ((ub >> 16) & 1u);
    return (ua >> 16) | (ub & 0xffff0000u);
}

// ---------------- Kernel 0: weight transpose + hi/lo split ----------------
__global__ __launch_bounds__(256) void prep_kernel(
    const float* __restrict__ wq, const float* __restrict__ wo,
    ushort_t* __restrict__ wT_hi, ushort_t* __restrict__ wT_lo,
    ushort_t* __restrict__ woT_hi, ushort_t* __restrict__ woT_lo)
{
    const int idx = blockIdx.x * 256 + threadIdx.x;   // 262144 = 192K + 64K
    if (idx < 192 * 1024) {
        const int c = idx >> 10, k = idx & 1023;
        ushort_t h, l; split2(wq[k * 192 + c], h, l);
        wT_hi[idx] = h; wT_lo[idx] = l;
    } else {
        const int j = idx - 192 * 1024;
        const int c = j >> 6, k = j & 63;
        ushort_t h, l; split2(wo[k * ODIM + c], h, l);
        woT_hi[j] = h; woT_lo[j] = l;
    }
}

// ---------------- Kernel 1: QKV projection (MFMA hi/lo) ----------------
// grid 1536 x 256. row_tile = bb & 511 (stride-512 siblings share an XCD ->
// L2-local x reuse); ctid = (bb>>9)*4 + wv. q is pre-scaled by log2e.
__global__ __launch_bounds__(256) void qkv_kernel(
    const float* __restrict__ x,
    const ushort_t* __restrict__ wT_hi, const ushort_t* __restrict__ wT_lo,
    const float* __restrict__ b,
    ushort_t* __restrict__ q_hi, ushort_t* __restrict__ q_lo,
    ushort_t* __restrict__ k_hi, ushort_t* __restrict__ k_lo,
    ushort_t* __restrict__ vT)
{
    const int tid = threadIdx.x;
    const int wv = tid >> 6, lane = tid & 63, g = lane >> 4, i = lane & 15;
    const int bb = (int)blockIdx.x;
    const int R0 = (bb & 511) * 16;
    const int ctid = (bb >> 9) * 4 + wv;   // 0..11
    const f32x4 zero4 = {0.f, 0.f, 0.f, 0.f};
    f32x4 acc = zero4;
    const float* xp = &x[(size_t)(R0 + i) * DM + g * 8];
    const ushort_t* bhp = &wT_hi[(ctid * 16 + i) * DM + g * 8];
    const ushort_t* blp = &wT_lo[(ctid * 16 + i) * DM + g * 8];

    for (int kc = 0; kc < 32; ++kc) {
        const float4 xa = *(const float4*)(xp + kc * 32);
        const float4 xb = *(const float4*)(xp + kc * 32 + 4);
        const float xe[8] = {xa.x, xa.y, xa.z, xa.w, xb.x, xb.y, xb.z, xb.w};
        union { short8 v; ushort_t u[8]; } ah, al;
#pragma unroll
        for (int j = 0; j < 8; ++j) { split2(xe[j], ah.u[j], al.u[j]); }
        const short8 bh = *(const short8*)(bhp + kc * 32);
        const short8 bl = *(const short8*)(blp + kc * 32);
        acc = MFMA16(ah.v, bh, acc);
        acc = MFMA16(ah.v, bl, acc);
        acc = MFMA16(al.v, bh, acc);
    }
    const int c = ctid * 16 + i;
    const float bias = b[c];
    if (ctid < 4) {          // q: pre-scale by log2e (softmax in exp2 domain)
#pragma unroll
        for (int reg = 0; reg < 4; ++reg) {
            ushort_t h, l; split2((acc[reg] + bias) * LOG2E, h, l);
            q_hi[(R0 + 4 * g + reg) * KD + c] = h;
            q_lo[(R0 + 4 * g + reg) * KD + c] = l;
        }
    } else if (ctid < 8) {   // k
        const int c2 = c - 64;
#pragma unroll
        for (int reg = 0; reg < 4; ++reg) {
            ushort_t h, l; split2(acc[reg] + bias, h, l);
            k_hi[(R0 + 4 * g + reg) * KD + c2] = h;
            k_lo[(R0 + 4 * g + reg) * KD + c2] = l;
        }
    } else {                 // v -> transposed bf16
        union { ushort_t u[4]; uint2 v; } pk;
#pragma unroll
        for (int reg = 0; reg < 4; ++reg) pk.u[reg] = rne(acc[reg] + bias);
        *(uint2*)&vT[(size_t)(c - 128) * N_TOK + R0 + 4 * g] = pk.v;
    }
}

// ---------------- Kernel 2: split-K causal flash attention (S^T form) ----------------
// grid 2048 x 256. wu=blockIdx.x: qt=511-(wu>>2) (heavy first), s=wu&3.
// Permuted key->tile map: tile ct holds keys 32(ct>>1)+4(ct&1)+8g+reg, so the
// P^T B-fragment for O^T = V^T P^T is the lane's own registers repacked.
// Writes UNNORMALIZED partial (M, L, O). No barriers/LDS in K-loop.
__global__ __launch_bounds__(256) void attn_kernel(
    const ushort_t* __restrict__ q_hi, const ushort_t* __restrict__ q_lo,
    const ushort_t* __restrict__ k_hi, const ushort_t* __restrict__ k_lo,
    const ushort_t* __restrict__ vT,
    float* __restrict__ Opart, float* __restrict__ MLpart,
    const int* __restrict__ causal_p)
{
    __shared__ float Om[4 * 1088];   // [wv][d:64][qrow:16 pad 17]
    __shared__ float ml[128];        // [wv][m:16 | l:16]

    const int tid = threadIdx.x;
    const int wv = tid >> 6, lane = tid & 63, g = lane >> 4, i = lane & 15;
    const int causal = *causal_p;
    const f32x4 zero4 = {0.f, 0.f, 0.f, 0.f};
    const int koff[4] = {0, 4, 32, 36};
    const int ibase = ((i >> 2) << 3) + (i & 3);

    const int wu = (int)blockIdx.x;
    const int qt = 511 - (wu >> 2);
    const int s = wu & 3;
    const int R0 = qt << 4;
    const int nkt = causal ? (R0 >> 6) + 1 : (N_TOK / 64);
    const int c0 = (s * nkt) >> 2, c1 = ((s + 1) * nkt) >> 2;

    const short8 qh0 = *(const short8*)&q_hi[(R0 + i) * KD + g * 8];
    const short8 qh1 = *(const short8*)&q_hi[(R0 + i) * KD + 32 + g * 8];
    const short8 ql0 = *(const short8*)&q_lo[(R0 + i) * KD + g * 8];
    const short8 ql1 = *(const short8*)&q_lo[(R0 + i) * KD + 32 + g * 8];

    f32x4 o4[4] = {zero4, zero4, zero4, zero4};
    float runm = -1e30f, runl = 0.f;

    for (int t = c0 + wv; t < c1; t += 4) {
        const int kb = t << 6;
        f32x4 s4[4];
#pragma unroll
        for (int ct = 0; ct < 4; ++ct) {
            const int row = (kb + koff[ct] + ibase) * KD;
            const short8 kh0 = *(const short8*)&k_hi[row + g * 8];
            const short8 kh1 = *(const short8*)&k_hi[row + 32 + g * 8];
            const short8 kl0 = *(const short8*)&k_lo[row + g * 8];
            const short8 kl1 = *(const short8*)&k_lo[row + 32 + g * 8];
            f32x4 a = MFMA16(kh0, qh0, zero4);
            a = MFMA16(kh1, qh1, a);
            a = MFMA16(kh0, ql0, a);
            a = MFMA16(kh1, ql1, a);
            a = MFMA16(kl0, qh0, a);
            a = MFMA16(kl1, qh1, a);
            s4[ct] = a;
        }
        if (causal && (kb + 64 > R0)) {  // diagonal tile only
#pragma unroll
            for (int ct = 0; ct < 4; ++ct)
#pragma unroll
                for (int reg = 0; reg < 4; ++reg) {
                    const int key = kb + koff[ct] + (g << 3) + reg;
                    s4[ct][reg] = (key <= R0 + i) ? s4[ct][reg] : -1e30f;
                }
        }
        // online softmax: lane owns qrow i; scalar state
        float mx = -1e30f;
#pragma unroll
        for (int ct = 0; ct < 4; ++ct)
#pragma unroll
            for (int reg = 0; reg < 4; ++reg) mx = fmaxf(mx, s4[ct][reg]);
        mx = fmaxf(mx, __shfl_xor(mx, 16));
        mx = fmaxf(mx, __shfl_xor(mx, 32));
        const float nm = fmaxf(runm, mx);
        const float al = ex2(runm - nm);
        runm = nm;
        float rs = 0.f;
#pragma unroll
        for (int ct = 0; ct < 4; ++ct)
#pragma unroll
            for (int reg = 0; reg < 4; ++reg) {
                const float p = ex2(s4[ct][reg] - nm);
                s4[ct][reg] = p;
                rs += p;
            }
        rs += __shfl_xor(rs, 16);
        rs += __shfl_xor(rs, 32);
        runl = runl * al + rs;
#pragma unroll
        for (int ct2 = 0; ct2 < 4; ++ct2)
#pragma unroll
            for (int reg = 0; reg < 4; ++reg) o4[ct2][reg] *= al;
        // P^T B-frags: pure register repack
        short8 pb0, pb1;
        {
            union { unsigned w[4]; short8 v; } u;
            u.w[0] = bfpack(s4[0][0], s4[0][1]); u.w[1] = bfpack(s4[0][2], s4[0][3]);
            u.w[2] = bfpack(s4[1][0], s4[1][1]); u.w[3] = bfpack(s4[1][2], s4[1][3]);
            pb0 = u.v;
            u.w[0] = bfpack(s4[2][0], s4[2][1]); u.w[1] = bfpack(s4[2][2], s4[2][3]);
            u.w[2] = bfpack(s4[3][0], s4[3][1]); u.w[3] = bfpack(s4[3][2], s4[3][3]);
            pb1 = u.v;
        }
#pragma unroll
        for (int ct2 = 0; ct2 < 4; ++ct2) {
            const int vrow = (ct2 * 16 + i) * N_TOK + kb;
            const short8 va0 = *(const short8*)&vT[vrow + g * 8];
            const short8 va1 = *(const short8*)&vT[vrow + 32 + g * 8];
            o4[ct2] = MFMA16(va0, pb0, o4[ct2]);
            o4[ct2] = MFMA16(va1, pb1, o4[ct2]);
        }
    }

    // 4-wave combine -> unnormalized partial (qt, s)
#pragma unroll
    for (int ct2 = 0; ct2 < 4; ++ct2)
#pragma unroll
        for (int reg = 0; reg < 4; ++reg)
            Om[wv * 1088 + (ct2 * 16 + 4 * g + reg) * 17 + i] = o4[ct2][reg];
    if (lane < 16) {
        ml[wv * 32 + lane] = runm;
        ml[wv * 32 + 16 + lane] = runl;
    }
    __syncthreads();
    {
        const int d = tid & 63, rb2 = (tid >> 6) << 2;
        const int pidx = (qt << 2) + s;
#pragma unroll
        for (int rr = 0; rr < 4; ++rr) {
            const int r = rb2 + rr;
            const float m0 = ml[r],      m1 = ml[32 + r];
            const float m2 = ml[64 + r], m3 = ml[96 + r];
            const float M = fmaxf(fmaxf(m0, m1), fmaxf(m2, m3));
            const float e0 = ex2(m0 - M), e1 = ex2(m1 - M);
            const float e2 = ex2(m2 - M), e3 = ex2(m3 - M);
            const float L = ml[16 + r] * e0 + ml[48 + r] * e1 +
                            ml[80 + r] * e2 + ml[112 + r] * e3;
            const float O = Om[d * 17 + r] * e0 +
                            Om[1088 + d * 17 + r] * e1 +
                            Om[2176 + d * 17 + r] * e2 +
                            Om[3264 + d * 17 + r] * e3;
            Opart[((size_t)pidx * 16 + r) * 64 + d] = O;
            if (d == 0) {
                MLpart[pidx * 32 + r] = M;
                MLpart[pidx * 32 + 16 + r] = L;
            }
        }
    }
}

// ---------------- Kernel 3: fused split-K merge + output projection ----------------
// grid 2048 x 256. Block (qtile=b>>2, qa=b&3): merge 4 partials of qtile into
// LDS ao (bf16 hi/lo), then MFMA project col quarter qa.
__global__ __launch_bounds__(256) void proj_kernel(
    const float* __restrict__ Opart, const float* __restrict__ MLpart,
    const ushort_t* __restrict__ woT_hi, const ushort_t* __restrict__ woT_lo,
    const float* __restrict__ bo, float* __restrict__ out)
{
    __shared__ ushort_t aoh[16 * 72];
    __shared__ ushort_t aol[16 * 72];
    const int tid = threadIdx.x;
    const int wv = tid >> 6, lane = tid & 63, g = lane >> 4, i = lane & 15;
    const int bb = (int)blockIdx.x;
    const int qtile = bb >> 2, qa = bb & 3;
    const int R0 = qtile << 4;
    const f32x4 zero4 = {0.f, 0.f, 0.f, 0.f};
    {
        const int d = tid & 63, rb2 = (tid >> 6) << 2;
#pragma unroll
        for (int rr = 0; rr < 4; ++rr) {
            const int r = rb2 + rr;
            float m[4], l[4];
#pragma unroll
            for (int s2 = 0; s2 < 4; ++s2) {
                m[s2] = MLpart[((qtile << 2) + s2) * 32 + r];
                l[s2] = MLpart[((qtile << 2) + s2) * 32 + 16 + r];
            }
            const float M = fmaxf(fmaxf(m[0], m[1]), fmaxf(m[2], m[3]));
            float den = 0.f, O = 0.f;
#pragma unroll
            for (int s2 = 0; s2 < 4; ++s2) {
                const float e = ex2(m[s2] - M);
                den += l[s2] * e;
                O += Opart[((size_t)((qtile << 2) + s2) * 16 + r) * 64 + d] * e;
            }
            ushort_t h, lo2; split2(O / den, h, lo2);
            aoh[r * 72 + d] = h;
            aol[r * 72 + d] = lo2;
        }
    }
    __syncthreads();
    {
        const short8 ah0 = *(const short8*)&aoh[i * 72 + g * 8];
        const short8 ah1 = *(const short8*)&aoh[i * 72 + 32 + g * 8];
        const short8 al0 = *(const short8*)&aol[i * 72 + g * 8];
        const short8 al1 = *(const short8*)&aol[i * 72 + 32 + g * 8];
#pragma unroll
        for (int cc = 0; cc < 4; ++cc) {
            const int col = (qa << 8) + ((wv << 2) + cc) * 16 + i;
            const short8 bh0 = *(const short8*)&woT_hi[col * KD + g * 8];
            const short8 bh1 = *(const short8*)&woT_hi[col * KD + 32 + g * 8];
            const short8 bl0 = *(const short8*)&woT_lo[col * KD + g * 8];
            const short8 bl1 = *(const short8*)&woT_lo[col * KD + 32 + g * 8];
            f32x4 acc = MFMA16(ah0, bh0, zero4);
            acc = MFMA16(ah1, bh1, acc);
            acc = MFMA16(ah0, bl0, acc);
            acc = MFMA16(ah1, bl1, acc);
            acc = MFMA16(al0, bh0, acc);
            acc = MFMA16(al1, bh1, acc);
            const float bias = bo[col];
#pragma unroll
            for (int reg = 0; reg < 4; ++reg)
                out[(size_t)(R0 + 4 * g + reg) * ODIM + col] = acc[reg] + bias;
        }
    }
}

extern "C" void kernel_launch(void* const* d_in, const int* in_sizes, int n_in,
                              void* d_out, int out_size, void* d_ws, size_t ws_size,
                              hipStream_t stream) {
    const float* x     = (const float*)d_in[0];
    const float* w_qkv = (const float*)d_in[1];
    const float* b_qkv = (const float*)d_in[2];
    const float* w_out = (const float*)d_in[3];
    const float* b_out = (const float*)d_in[4];
    const int* causal  = (const int*)d_in[5];
    float* out         = (float*)d_out;

    char* ws = (char*)d_ws;
    ushort_t* wT_hi  = (ushort_t*)(ws);                    // 384 KB
    ushort_t* wT_lo  = (ushort_t*)(ws + 393216);           // 384 KB
    ushort_t* woT_hi = (ushort_t*)(ws + 786432);           // 128 KB
    ushort_t* woT_lo = (ushort_t*)(ws + 917504);           // 128 KB -> 1 MB
    ushort_t* q_hi   = (ushort_t*)(ws + (1u << 20));
    ushort_t* q_lo   = (ushort_t*)(ws + (2u << 20));
    ushort_t* k_hi   = (ushort_t*)(ws + (3u << 20));
    ushort_t* k_lo   = (ushort_t*)(ws + (4u << 20));
    ushort_t* vT     = (ushort_t*)(ws + (5u << 20));       // -> 6 MB
    float*    Opart  = (float*)(ws + (6u << 20));          // 8 MB -> 14 MB
    float*    MLpart = (float*)(ws + (14u << 20));         // 256 KB

    prep_kernel<<<1024, 256, 0, stream>>>(w_qkv, w_out, wT_hi, wT_lo, woT_hi, woT_lo);
    qkv_kernel<<<1536, 256, 0, stream>>>(x, wT_hi, wT_lo, b_qkv, q_hi, q_lo, k_hi, k_lo, vT);
    attn_kernel<<<2048, 256, 0, stream>>>(q_hi, q_lo, k_hi, k_lo, vT, Opart, MLpart, causal);
    proj_kernel<<<2048, 256, 0, stream>>>(Opart, MLpart, woT_hi, woT_lo, b_out, out);
}